// Round 1
// baseline (6296.007 us; speedup 1.0000x reference)
//
#include <hip/hip_runtime.h>
#include <stdint.h>
#include <math.h>

// ---------------- problem constants ----------------
#define BB 32
#define TT 1024
#define CIN 128
#define FF 256
#define KW 5
#define HH 512
#define TP 510          // conv output length (VALID, stride 2)
#define TLAST 509
#define NPAD 16384      // padded (t',b) count (512*32)
#define KC 640          // conv GEMM K  (5*128)
#define G4 2048         // 4*H
#define GWG 64          // scan workgroups (8 hidden units each)

// ---------------- workspace layout (bytes) ----------------
// sync region (memset to 0 every launch):
#define FLAGS_OFF   0u            // 64 flags, 64B stride -> 4096
#define HH_OFF      4096u         // h hi bf16, double buffered: 2*32*512*2 = 65536
#define HL_OFF      69632u        // h lo bf16: 65536
#define PARTS_OFF   135168u       // du partials: 2*32*64*4 = 16384
#define SYNC_BYTES  151552u
// big buffers:
#define XP_OFF      151552ull                         // fp32 [2048][16384] = 134217728
#define XH_OFF      (XP_OFF + 134217728ull)           // x hi bf16 [4194304]
#define XL_OFF      (XH_OFF + 8388608ull)
#define XSH_OFF     (XL_OFF + 8388608ull)             // xs hi bf16 [16384][256]
#define XSL_OFF     (XSH_OFF + 8388608ull)
#define WCH_OFF     (XSL_OFF + 8388608ull)            // conv W [256][640] hi
#define WCL_OFF     (WCH_OFF + 327680ull)
#define WIHH_OFF    (WCL_OFF + 327680ull)             // w_ih [2048][256] hi
#define WIHL_OFF    (WIHH_OFF + 1048576ull)
#define WS_NEED     (WIHL_OFF + 1048576ull)           // ~163 MiB

typedef unsigned short u16;
typedef __attribute__((ext_vector_type(8))) short short8;
typedef __attribute__((ext_vector_type(4))) float f32x4;

__device__ __forceinline__ u16 f2bf(float f) {
  uint32_t u = __float_as_uint(f);
  u += 0x7fffu + ((u >> 16) & 1u);      // RNE
  return (u16)(u >> 16);
}
__device__ __forceinline__ float bf2f(u16 s) { return __uint_as_float(((uint32_t)s) << 16); }
__device__ __forceinline__ void splitf(float v, u16& h, u16& l) {
  h = f2bf(v);
  l = f2bf(v - bf2f(h));
}
__device__ __forceinline__ float sigm(float x) { return 1.f / (1.f + expf(-x)); }

// ---------------- prep: split x / conv_w(transposed) / w_ih into bf16 hi+lo ----------------
__global__ void prep_kernel(const float* __restrict__ x, const float* __restrict__ conv_w,
                            const float* __restrict__ w_ih,
                            u16* __restrict__ xh, u16* __restrict__ xl,
                            u16* __restrict__ wch, u16* __restrict__ wcl,
                            u16* __restrict__ wihh, u16* __restrict__ wihl) {
  int i = blockIdx.x * 256 + threadIdx.x;
  if (i < 4194304) {
    u16 h, l; splitf(x[i], h, l); xh[i] = h; xl[i] = l;
  } else if (i < 4194304 + 163840) {
    int j = i - 4194304;
    int f = j / 640, kk = j % 640;
    int c = kk & 127, k = kk >> 7;                 // kk = k*128 + c
    u16 h, l; splitf(conv_w[f * 640 + c * 5 + k], h, l);
    wch[f * 640 + kk] = h; wcl[f * 640 + kk] = l;
  } else if (i < 4194304 + 163840 + 524288) {
    int j = i - (4194304 + 163840);
    u16 h, l; splitf(w_ih[j], h, l); wihh[j] = h; wihl[j] = l;
  }
}

// ---------------- split-bf16 GEMM, 128x128 tile, BK=32, frag-order LDS ----------------
// MODE 0: conv  (K=640, B = windowed x, epilogue relu+BN -> xs hi/lo bf16 at [n][f])
// MODE 1: proj  (K=256, B = xs rows,    epilogue +bias   -> xp fp32 at [g][n])
template <int MODE>
__global__ __launch_bounds__(256, 1) void gemm_kernel(
    const u16* __restrict__ Ah, const u16* __restrict__ Al,
    const u16* __restrict__ Bh, const u16* __restrict__ Bl,
    const float* __restrict__ e0, const float* __restrict__ e1,
    const float* __restrict__ e2, const float* __restrict__ e3, const float* __restrict__ e4,
    u16* __restrict__ outh, u16* __restrict__ outl, float* __restrict__ outf) {
  const int KDIM = (MODE == 0) ? KC : 256;
  const int MT   = (MODE == 0) ? 2 : 16;
  int bx = blockIdx.x;
  int m0 = (bx % MT) * 128;
  int n0 = (bx / MT) * 128;
  __shared__ __attribute__((aligned(16))) u16 lds[4][4096]; // Ah Al Bh Bl, 512 entries x 8 bf16
  int t = threadIdx.x;
  int wave = t >> 6, lane = t & 63;
  int wm = wave & 1, wn = wave >> 1;

  f32x4 acc[4][4];
#pragma unroll
  for (int i = 0; i < 4; i++)
#pragma unroll
    for (int j = 0; j < 4; j++) acc[i][j] = (f32x4){0.f, 0.f, 0.f, 0.f};

  for (int k0 = 0; k0 < KDIM; k0 += 32) {
    __syncthreads();
    // stage: entries e: tile = e>>6 (0..7), l = e&63; lane layout matches MFMA frags
#pragma unroll
    for (int half = 0; half < 2; half++) {
      int e = half * 256 + t;
      int l = e & 63, tile = e >> 6;
      int kk = k0 + ((l >> 4) * 8);
      {
        int row = m0 + tile * 16 + (l & 15);
        const u16* sh = Ah + (long)row * KDIM + kk;
        const u16* sl = Al + (long)row * KDIM + kk;
        *(short8*)&lds[0][e * 8] = *(const short8*)sh;
        *(short8*)&lds[1][e * 8] = *(const short8*)sl;
      }
      {
        int n = n0 + tile * 16 + (l & 15);
        long base;
        if (MODE == 0) {
          int tp = n >> 5; if (tp > TLAST) tp = TLAST;   // clamp pad region
          base = (long)(n & 31) * 131072 + (long)tp * 256;
        } else {
          base = (long)n * 256;
        }
        *(short8*)&lds[2][e * 8] = *(const short8*)(Bh + base + kk);
        *(short8*)&lds[3][e * 8] = *(const short8*)(Bl + base + kk);
      }
    }
    __syncthreads();
    short8 af[4][2], bf[4][2];
#pragma unroll
    for (int i = 0; i < 4; i++) {
      af[i][0] = *(const short8*)&lds[0][((wm * 4 + i) * 64 + lane) * 8];
      af[i][1] = *(const short8*)&lds[1][((wm * 4 + i) * 64 + lane) * 8];
      bf[i][0] = *(const short8*)&lds[2][((wn * 4 + i) * 64 + lane) * 8];
      bf[i][1] = *(const short8*)&lds[3][((wn * 4 + i) * 64 + lane) * 8];
    }
#pragma unroll
    for (int am = 0; am < 4; am++)
#pragma unroll
      for (int an = 0; an < 4; an++) {
        acc[am][an] = __builtin_amdgcn_mfma_f32_16x16x32_bf16(af[am][0], bf[an][0], acc[am][an], 0, 0, 0);
        acc[am][an] = __builtin_amdgcn_mfma_f32_16x16x32_bf16(af[am][0], bf[an][1], acc[am][an], 0, 0, 0);
        acc[am][an] = __builtin_amdgcn_mfma_f32_16x16x32_bf16(af[am][1], bf[an][0], acc[am][an], 0, 0, 0);
      }
  }
  // epilogue: D element (row m, col n): m = (lane>>4)*4 + r within tile, n = lane&15
#pragma unroll
  for (int am = 0; am < 4; am++)
#pragma unroll
    for (int an = 0; an < 4; an++) {
      int n = n0 + (wn * 4 + an) * 16 + (lane & 15);
#pragma unroll
      for (int r = 0; r < 4; r++) {
        int m = m0 + (wm * 4 + am) * 16 + (lane >> 4) * 4 + r;
        float v = acc[am][an][r];
        if (MODE == 0) {
          float inv = e1[m] / sqrtf(e4[m] + 1e-5f);
          float sh  = e2[m] - e3[m] * inv;
          v = fmaxf(v + e0[m], 0.f) * inv + sh;
          u16 h, l; splitf(v, h, l);
          outh[(long)n * 256 + m] = h;
          outl[(long)n * 256 + m] = l;
        } else {
          v += e0[m] + e1[m];
          outf[(long)m * NPAD + n] = v;
        }
      }
    }
}

// ---------------- persistent skip-LSTM scan ----------------
// 64 wgs x 256 thr. wg owns hidden units j in [8*wg, 8*wg+8) -> 32 rows of W_hh
// (i,f,g,o), kept as pre-split MFMA A-frags in registers. h published per step as
// bf16 hi/lo streams; cross-wg sync via per-wg monotonic flags (agent scope).
__global__ __launch_bounds__(256, 1) void scan_kernel(
    const float* __restrict__ xp,     // [2048][NPAD]
    const float* __restrict__ w_hh,   // [2048][512]
    const float* __restrict__ w_uh,   // [512]
    const float* __restrict__ b_uh_p, // [1]
    u16* __restrict__ hh,             // [2][32][512] hi
    u16* __restrict__ hl,             // [2][32][512] lo
    float* __restrict__ parts,        // [2][32][64]
    uint32_t* __restrict__ flags,     // [64][16] (64B stride)
    float* __restrict__ outp)         // [32][512]
{
  __shared__ float gl[32][33];
  __shared__ float u_l[32], ubin_l[32];
  __shared__ float wuh_l[8];
  int wg = blockIdx.x, t = threadIdx.x;
  int wave = t >> 6, lane = t & 63;
  int mt = wave & 1, nt = wave >> 1;

  if (t < 8)  wuh_l[t] = w_uh[wg * 8 + t];
  if (t < 32) { u_l[t] = 1.0f; ubin_l[t] = 1.0f; }

  // preload W_hh fragments (constant all steps): rows for this wave's M-tile
  int m = lane & 15, jj_w = m & 7;
  int q = mt * 2 + (m >> 3);                 // gate block 0..3 (i,f,g,o)
  long grow = (long)(q * 512 + wg * 8 + jj_w) * 512;
  short8 wfh[16], wfl[16];
#pragma unroll
  for (int ks = 0; ks < 16; ks++) {
    int kbase = ks * 32 + (lane >> 4) * 8;
    union { short8 v; u16 u[8]; } Uh, Ul;
#pragma unroll
    for (int i = 0; i < 8; i++) splitf(w_hh[grow + kbase + i], Uh.u[i], Ul.u[i]);
    wfh[ks] = Uh.v; wfl[ks] = Ul.v;
  }
  float bu = b_uh_p[0];

  // per-cell state in registers: cell (jj = t&7, b = t>>3)
  int pjj = t & 7, pb = t >> 3;
  float c_reg = 0.f, h_reg = 0.f;

  float xr[4];
#pragma unroll
  for (int qq = 0; qq < 4; qq++)
    xr[qq] = xp[(long)(qq * 512 + wg * 8 + pjj) * NPAD + pb];   // step 0
  __syncthreads();

  for (int s = 0; s < TP; s++) {
    int par = s & 1, np = par ^ 1;
    if (s > 0) {
      if (t < GWG) {
        while (__hip_atomic_load(&flags[t * 16], __ATOMIC_RELAXED, __HIP_MEMORY_SCOPE_AGENT) < (uint32_t)s)
          __builtin_amdgcn_s_sleep(1);
      }
      __syncthreads();
      __threadfence();   // acquire: invalidate stale L1/L2 before reading h/parts
      if (t < 32) {      // u-update from step s-1 partials (identical in every wg)
        const f32x4* pp = (const f32x4*)(parts + par * 2048 + t * 64);
        float a = 0.f;
#pragma unroll
        for (int i = 0; i < 16; i++) { f32x4 v = pp[i]; a += v.x; a += v.y; a += v.z; a += v.w; }
        float du = sigm(a + bu);
        float up = u_l[t], ubp = ubin_l[t];
        float un = (ubp > 0.5f) ? du : (up + fminf(du, 1.f - up));
        u_l[t] = un; ubin_l[t] = rintf(un);
      }
    }
    // MFMA: gates tile [16 rows x 16 batch], B-frags straight from global hi/lo streams
    const u16* bh_p = hh + par * 16384 + (nt * 16 + (lane & 15)) * 512 + (lane >> 4) * 8;
    const u16* bl_p = hl + par * 16384 + (nt * 16 + (lane & 15)) * 512 + (lane >> 4) * 8;
    f32x4 acc = (f32x4){0.f, 0.f, 0.f, 0.f};
#pragma unroll
    for (int ks = 0; ks < 16; ks++) {
      short8 bh = *(const short8*)(bh_p + ks * 32);
      short8 bl = *(const short8*)(bl_p + ks * 32);
      acc = __builtin_amdgcn_mfma_f32_16x16x32_bf16(wfh[ks], bh, acc, 0, 0, 0);
      acc = __builtin_amdgcn_mfma_f32_16x16x32_bf16(wfh[ks], bl, acc, 0, 0, 0);
      acc = __builtin_amdgcn_mfma_f32_16x16x32_bf16(wfl[ks], bh, acc, 0, 0, 0);
    }
    // prefetch next step's xp slice (independent of recurrence)
    float xr2[4] = {0.f, 0.f, 0.f, 0.f};
    if (s < TLAST) {
#pragma unroll
      for (int qq = 0; qq < 4; qq++)
        xr2[qq] = xp[(long)(qq * 512 + wg * 8 + pjj) * NPAD + (s + 1) * 32 + pb];
    }
    {
      int col = nt * 16 + (lane & 15);
      int rb = mt * 16 + (lane >> 4) * 4;
#pragma unroll
      for (int r = 0; r < 4; r++) gl[rb + r][col] = acc[r];
    }
    __syncthreads();
    // epilogue: one LSTM cell per thread
    {
      float gi = gl[pjj][pb]      + xr[0];
      float gf = gl[8 + pjj][pb]  + xr[1];
      float gg = gl[16 + pjj][pb] + xr[2];
      float go = gl[24 + pjj][pb] + xr[3];
      float ig = sigm(gi), fg = sigm(gf), og = sigm(go);
      float gt = tanhf(gg);
      float ct = fg * c_reg + ig * gt;
      float ht = og * tanhf(ct);
      bool upd = ubin_l[pb] > 0.5f;
      float cn = upd ? ct : c_reg;
      float hn = upd ? ht : h_reg;
      c_reg = cn; h_reg = hn;
      u16 hhi, hlo; splitf(hn, hhi, hlo);
      long ho = (long)np * 16384 + pb * 512 + wg * 8 + pjj;
      hh[ho] = hhi; hl[ho] = hlo;
      float p = cn * wuh_l[pjj];
      p += __shfl_xor(p, 1); p += __shfl_xor(p, 2); p += __shfl_xor(p, 4);
      if (pjj == 0) parts[np * 2048 + pb * 64 + wg] = p;
      if (s == TLAST) outp[pb * 512 + wg * 8 + pjj] = hn;
      xr[0] = xr2[0]; xr[1] = xr2[1]; xr[2] = xr2[2]; xr[3] = xr2[3];
    }
    __syncthreads();
    if (t == 0) {
      __threadfence();  // release: write back L2 so other XCDs see h/parts
      __hip_atomic_store(&flags[wg * 16], (uint32_t)(s + 1), __ATOMIC_RELEASE, __HIP_MEMORY_SCOPE_AGENT);
    }
  }
}

// ---------------- launcher ----------------
extern "C" void kernel_launch(void* const* d_in, const int* in_sizes, int n_in,
                              void* d_out, int out_size, void* d_ws, size_t ws_size,
                              hipStream_t stream) {
  const float* x      = (const float*)d_in[0];
  const float* conv_w = (const float*)d_in[1];
  const float* conv_b = (const float*)d_in[2];
  const float* gamma  = (const float*)d_in[3];
  const float* beta   = (const float*)d_in[4];
  const float* mean   = (const float*)d_in[5];
  const float* var    = (const float*)d_in[6];
  const float* w_ih   = (const float*)d_in[7];
  const float* w_hh   = (const float*)d_in[8];
  const float* b_ih   = (const float*)d_in[9];
  const float* b_hh   = (const float*)d_in[10];
  const float* w_uh   = (const float*)d_in[11];
  const float* b_uh   = (const float*)d_in[12];
  float* out = (float*)d_out;

  if (ws_size < WS_NEED) return;  // workspace too small: fail visibly via absmax

  char* w = (char*)d_ws;
  uint32_t* flags = (uint32_t*)(w + FLAGS_OFF);
  u16*   hhb   = (u16*)(w + HH_OFF);
  u16*   hlb   = (u16*)(w + HL_OFF);
  float* parts = (float*)(w + PARTS_OFF);
  float* xp    = (float*)(w + XP_OFF);
  u16*   xh    = (u16*)(w + XH_OFF);
  u16*   xl    = (u16*)(w + XL_OFF);
  u16*   xsh   = (u16*)(w + XSH_OFF);
  u16*   xsl   = (u16*)(w + XSL_OFF);
  u16*   wch   = (u16*)(w + WCH_OFF);
  u16*   wcl   = (u16*)(w + WCL_OFF);
  u16*   wihh  = (u16*)(w + WIHH_OFF);
  u16*   wihl  = (u16*)(w + WIHL_OFF);

  hipMemsetAsync(d_ws, 0, SYNC_BYTES, stream);  // flags + h0 + partials = 0

  prep_kernel<<<19072, 256, 0, stream>>>(x, conv_w, w_ih, xh, xl, wch, wcl, wihh, wihl);

  // conv GEMM: M=256(f) N=16384 K=640 -> xs (relu+BN, bf16 hi/lo, [n][f])
  gemm_kernel<0><<<2 * 128, 256, 0, stream>>>(wch, wcl, xh, xl,
                                              conv_b, gamma, beta, mean, var,
                                              xsh, xsl, nullptr);
  // proj GEMM: M=2048(g) N=16384 K=256 -> xp fp32 [g][n] (+ b_ih + b_hh)
  gemm_kernel<1><<<16 * 128, 256, 0, stream>>>(wihh, wihl, xsh, xsl,
                                               b_ih, b_hh, nullptr, nullptr, nullptr,
                                               nullptr, nullptr, xp);
  // persistent scan
  scan_kernel<<<GWG, 256, 0, stream>>>(xp, w_hh, w_uh, b_uh, hhb, hlb, parts, flags, out);
}